// Round 5
// baseline (65.304 us; speedup 1.0000x reference)
//
#include <hip/hip_runtime.h>

// TransfPropModule — cooperative-gather version.
//
// Round-4 lesson: per-lane row gather (4 vec4, 64 distinct lines per wave
// instr) left us at 63 us vs ~49 us stream floor. Fix: 4 lanes cooperate on
// one point's 64 B row -> 16 distinct lines per wave instr (TCP merges the
// 4 same-line lane requests). Row quads scatter straight into s_R/s_t in
// output layout; R@pos is computed cooperatively via a quad shfl_xor
// butterfly; w broadcasts from the q=3 lane.

typedef float f4 __attribute__((ext_vector_type(4)));

__global__ void __launch_bounds__(256)
prepack_kernel(const float* __restrict__ cw,
               const float* __restrict__ Rm,
               const float* __restrict__ tm,
               float* __restrict__ packed,
               int M)
{
    int i = blockIdx.x * 256 + threadIdx.x;   // element index into packed
    if (i >= M * 16) return;
    int r = i >> 4, j = i & 15;
    float v = 0.0f;
    if (j < 9)       v = Rm[r * 9 + j];
    else if (j < 12) v = tm[r * 3 + (j - 9)];
    else if (j == 12) v = cw[r];
    packed[i] = v;
}

__global__ void __launch_bounds__(256)
transf_prop_kernel(const float* __restrict__ x,
                   const float* __restrict__ pos,
                   const float* __restrict__ packed,
                   const int*   __restrict__ cidx,
                   float* __restrict__ Rp,
                   float* __restrict__ tp,
                   float* __restrict__ xo,
                   int n)
{
    __shared__ __align__(16) float s_pos[768];
    __shared__ __align__(16) float s_x[768];
    __shared__ __align__(16) float s_R[2304];
    __shared__ __align__(16) float s_t[768];
    __shared__ __align__(16) float s_o[768];

    const int t    = threadIdx.x;
    const int base = blockIdx.x * 256;

    if (base + 256 <= n) {
        // ---------- fast path ----------
        const int sub = t >> 2;     // point-in-pass 0..63
        const int q   = t & 3;      // quad lane: which 16B of the 64B row

        // A1: issue all gather loads (cooperative: 4 lanes share one row ->
        // 16 distinct lines per wave instruction) + stage pos/x streams.
        const int c0 = cidx[base +       sub];
        const int c1 = cidx[base +  64 + sub];
        const int c2 = cidx[base + 128 + sub];
        const int c3 = cidx[base + 192 + sub];
        const f4* pk4 = (const f4*)packed;
        const f4 row0 = pk4[(size_t)c0 * 4 + q];
        const f4 row1 = pk4[(size_t)c1 * 4 + q];
        const f4 row2 = pk4[(size_t)c2 * 4 + q];
        const f4 row3 = pk4[(size_t)c3 * 4 + q];

        const f4* pos4 = (const f4*)(pos + (size_t)base * 3);
        const f4* x4   = (const f4*)(x   + (size_t)base * 3);
        if (t < 192) {
            ((f4*)s_pos)[t] = pos4[t];
            ((f4*)s_x)[t]   = x4[t];
        }
        __syncthreads();

        // A2: per pass: scatter R/t to LDS (output layout) + cooperative matvec
        #pragma unroll
        for (int g = 0; g < 4; ++g) {
            const int pt = g * 64 + sub;
            const f4 v = (g == 0) ? row0 : (g == 1) ? row1 : (g == 2) ? row2 : row3;

            if (q == 0) {        // r0 r1 r2 r3
                s_R[9*pt+0] = v.x; s_R[9*pt+1] = v.y;
                s_R[9*pt+2] = v.z; s_R[9*pt+3] = v.w;
            } else if (q == 1) { // r4 r5 r6 r7
                s_R[9*pt+4] = v.x; s_R[9*pt+5] = v.y;
                s_R[9*pt+6] = v.z; s_R[9*pt+7] = v.w;
            } else if (q == 2) { // r8 t0 t1 t2
                s_R[9*pt+8] = v.x;
                s_t[3*pt+0] = v.y; s_t[3*pt+1] = v.z; s_t[3*pt+2] = v.w;
            }                    // q==3: w - - -  (nothing to store)

            // partial products of pr = R @ pos + t, split across the quad
            const float p0 = s_pos[3*pt+0], p1 = s_pos[3*pt+1], p2 = s_pos[3*pt+2];
            float a0 = 0.f, a1 = 0.f, a2 = 0.f;
            if (q == 0) {
                a0 = fmaf(v.x, p0, fmaf(v.y, p1, v.z * p2));   // r0p0+r1p1+r2p2
                a1 = v.w * p0;                                  // r3p0
            } else if (q == 1) {
                a1 = fmaf(v.x, p1, v.y * p2);                   // r4p1+r5p2
                a2 = fmaf(v.z, p0, v.w * p1);                   // r6p0+r7p1
            } else if (q == 2) {
                a0 = v.y;                                       // t0
                a1 = v.z;                                       // t1
                a2 = fmaf(v.x, p2, v.w);                        // r8p2+t2
            }
            // quad butterfly sum (lanes t^1, t^2 are in the same quad)
            a0 += __shfl_xor(a0, 1); a1 += __shfl_xor(a1, 1); a2 += __shfl_xor(a2, 1);
            a0 += __shfl_xor(a0, 2); a1 += __shfl_xor(a1, 2); a2 += __shfl_xor(a2, 2);
            const float w   = __shfl(v.x, t | 3);   // w lives in the q==3 lane
            const float omw = 1.0f - w;

            if (q < 3) {
                const float pr = (q == 0) ? a0 : (q == 1) ? a1 : a2;
                const float xv = s_x[3*pt+q];
                s_o[3*pt+q] = fmaf(xv, w, pr * omw);
            }
        }
        __syncthreads();

        // C: vectorized non-temporal writeback
        f4* Rb4 = (f4*)(Rp + (size_t)base * 9);        // 2304 f = 576 vec4
        const f4* sR4 = (const f4*)s_R;
        __builtin_nontemporal_store(sR4[t],       &Rb4[t]);
        __builtin_nontemporal_store(sR4[t + 256], &Rb4[t + 256]);
        if (t < 64)
            __builtin_nontemporal_store(sR4[t + 512], &Rb4[t + 512]);

        f4* tb4 = (f4*)(tp + (size_t)base * 3);        // 192 vec4
        f4* ob4 = (f4*)(xo + (size_t)base * 3);
        if (t < 192) {
            __builtin_nontemporal_store(((const f4*)s_t)[t], &tb4[t]);
            __builtin_nontemporal_store(((const f4*)s_o)[t], &ob4[t]);
        }
    } else {
        // ---------- generic tail path (unused when n % 256 == 0) ----------
        const int m  = n - base;
        const int m3 = m * 3, m9 = m * 9;
        const float* posb = pos + (size_t)base * 3;
        const float* xb   = x   + (size_t)base * 3;
        for (int k = 0; k < 3; ++k) {
            int i = t + 256 * k;
            if (i < m3) { s_pos[i] = posb[i]; s_x[i] = xb[i]; }
        }
        __syncthreads();
        if (t < m) {
            const int c = cidx[base + t];
            const float* row = packed + (size_t)c * 16;
            float r[9];
            for (int j = 0; j < 9; ++j) r[j] = row[j];
            const float t0 = row[9], t1 = row[10], t2 = row[11];
            const float w  = row[12];
            const float p0 = s_pos[t*3], p1 = s_pos[t*3+1], p2 = s_pos[t*3+2];
            const float x0 = s_x[t*3],   x1 = s_x[t*3+1],   x2 = s_x[t*3+2];
            const float pr0 = fmaf(r[0], p0, fmaf(r[1], p1, fmaf(r[2], p2, t0)));
            const float pr1 = fmaf(r[3], p0, fmaf(r[4], p1, fmaf(r[5], p2, t1)));
            const float pr2 = fmaf(r[6], p0, fmaf(r[7], p1, fmaf(r[8], p2, t2)));
            const float omw = 1.0f - w;
            for (int j = 0; j < 9; ++j) s_R[t * 9 + j] = r[j];
            s_t[t*3] = t0; s_t[t*3+1] = t1; s_t[t*3+2] = t2;
            s_o[t*3]   = fmaf(x0, w, pr0 * omw);
            s_o[t*3+1] = fmaf(x1, w, pr1 * omw);
            s_o[t*3+2] = fmaf(x2, w, pr2 * omw);
        }
        __syncthreads();
        float* Rb = Rp + (size_t)base * 9;
        for (int k = 0; k < 9; ++k) {
            int i = t + 256 * k;
            if (i < m9) __builtin_nontemporal_store(s_R[i], &Rb[i]);
        }
        float* tb = tp + (size_t)base * 3;
        float* ob = xo + (size_t)base * 3;
        for (int k = 0; k < 3; ++k) {
            int i = t + 256 * k;
            if (i < m3) {
                __builtin_nontemporal_store(s_t[i], &tb[i]);
                __builtin_nontemporal_store(s_o[i], &ob[i]);
            }
        }
    }
}

extern "C" void kernel_launch(void* const* d_in, const int* in_sizes, int n_in,
                              void* d_out, int out_size, void* d_ws, size_t ws_size,
                              hipStream_t stream) {
    const float* x   = (const float*)d_in[0];
    const float* pos = (const float*)d_in[1];
    // d_in[2] = batch (unused by reference)
    const float* cw  = (const float*)d_in[3];
    const float* Rm  = (const float*)d_in[4];
    const float* tm  = (const float*)d_in[5];
    const int*  edge = (const int*)d_in[6];

    const int n = in_sizes[0] / 3;           // N points
    const int M = in_sizes[3];               // clusters (cluster_weights is [M,1])
    const int* cidx = edge + n;              // edge_index row 1 = cluster idx

    float* out = (float*)d_out;
    float* Rp = out;                          // [N,3,3]
    float* tp = out + (size_t)n * 9;          // [N,3]
    float* xo = out + (size_t)n * 12;         // [N,3]

    float* packed = (float*)d_ws;             // [M,16] floats = 1 MB

    const int block = 256;
    const int pgrid = (M * 16 + block - 1) / block;
    prepack_kernel<<<pgrid, block, 0, stream>>>(cw, Rm, tm, packed, M);

    const int grid = (n + block - 1) / block;
    transf_prop_kernel<<<grid, block, 0, stream>>>(x, pos, packed, cidx,
                                                   Rp, tp, xo, n);
}